// Round 12
// baseline (156.331 us; speedup 1.0000x reference)
//
#include <hip/hip_runtime.h>
#include <hip/hip_bf16.h>
#include <stdint.h>

typedef __bf16 bf16x8 __attribute__((ext_vector_type(8)));
typedef __bf16 bf16x4 __attribute__((ext_vector_type(4)));
typedef float  f32x4  __attribute__((ext_vector_type(4)));
typedef short  s16x4  __attribute__((ext_vector_type(4)));
typedef short  s16x8  __attribute__((ext_vector_type(8)));
typedef unsigned short u16_t;

#define MFMA(a, b, c)   __builtin_amdgcn_mfma_f32_16x16x32_bf16((a), (b), (c), 0, 0, 0)

// sync primitives (two-level stringize so macro args expand before #)
#define BAR()     asm volatile("s_barrier" ::: "memory")
#define WAITV_(N) asm volatile("s_waitcnt vmcnt(" #N ")" ::: "memory")
#define WAITV(N)  WAITV_(N)
#define WAITL()   asm volatile("s_waitcnt lgkmcnt(0)" ::: "memory")

// concat two s16x4 halves into a bf16x8 MFMA operand
__device__ __forceinline__ bf16x8 cat8(s16x4 a, s16x4 b) {
  s16x8 t = __builtin_shufflevector(a, b, 0, 1, 2, 3, 4, 5, 6, 7);
  return *(bf16x8*)&t;
}
__device__ __forceinline__ bf16x8 b8(s16x8 v) {
  bf16x8 r; __builtin_memcpy(&r, &v, 16); return r;
}

// async global->LDS, 16B per lane; LDS dest is wave-uniform base + lane*16
__device__ __forceinline__ void cp16(const void* g, void* l) {
  __builtin_amdgcn_global_load_lds(
      (const __attribute__((address_space(1))) unsigned int*)g,
      (__attribute__((address_space(3))) unsigned int*)l, 16, 0, 0);
}

// ---------------- kernel 1: fused x-convert + W-transpose-convert ----------------
__global__ __launch_bounds__(256) void k_prep(const float* __restrict__ x,
                                              const float* __restrict__ W0,
                                              const float* __restrict__ W1,
                                              const float* __restrict__ W2,
                                              u16_t* __restrict__ xb,
                                              u16_t* __restrict__ Wt) {
  __shared__ u16_t T[64][65];
  int bx = blockIdx.x, t = threadIdx.x;
  if (bx < 4096) {
    int i = bx * 256 + t;
    float4 f = ((const float4*)x)[i];
    bf16x4 o = {(__bf16)f.x, (__bf16)f.y, (__bf16)f.z, (__bf16)f.w};
    *(bf16x4*)&xb[(size_t)i * 4] = o;
    return;
  }
  int j = bx - 4096;
  int nx = j & 15, ny = (j >> 4) & 15, z = j >> 8;
  const float* W = z == 0 ? W0 : (z == 1 ? W1 : W2);
  int k0 = ny * 64, n0 = nx * 64;
#pragma unroll
  for (int i = 0; i < 16; i++) {
    int e = i * 256 + t, r = e >> 6, c = e & 63;
    __bf16 hv = (__bf16)W[(size_t)(k0 + r) * 1024 + n0 + c];
    T[r][c] = *(u16_t*)&hv;
  }
  __syncthreads();
  size_t base = ((size_t)z * 1024 + n0) * 1024 + k0;
#pragma unroll
  for (int i = 0; i < 16; i++) {
    int e = i * 256 + t, r = e >> 6, c = e & 63;
    Wt[base + (size_t)r * 1024 + c] = T[c][r];
  }
}

// ---------------- kernel 2: fused QKV GEMM, 256x192 tile, 8-wave, 2-barrier/tile ----------------
// (round-11 version, confirmed win: total -3.3 us, GEMM est. ~low-30s. Unchanged.)
__global__ __launch_bounds__(512, 2) void k_gemm_qkv(
    const u16_t* __restrict__ A, const u16_t* __restrict__ Bt,
    const float* __restrict__ bq, const float* __restrict__ bk,
    const float* __restrict__ bv,
    u16_t* __restrict__ Qo, u16_t* __restrict__ Ko, u16_t* __restrict__ Vo) {
  __shared__ u16_t smem[57344];          // 112 KB
  u16_t* As = smem;                      // [buf:16384][half:8192][row*32 + chunk*8], 256 rows
  u16_t* Bs = smem + 32768;              // [buf:12288][half:6144][row*32 + chunk*8], 192 rows

  const int tid = threadIdx.x, lane = tid & 63, wv = tid >> 6;
  const int quad = lane >> 4, col = lane & 15;
  const int wm = wv >> 2, wn = wv & 3;   // 2x4 wave grid; wave owns 128x48 of C

  // XCD swizzle: 256 blocks, 32 consecutive wg per XCD
  int bid = blockIdx.x;
  int wg = (bid & 7) * 32 + (bid >> 3);
  const int tn = (wg & 15) * 192, tm = (wg >> 4) << 8;

  const int r16 = lane >> 2, c4 = lane & 3;
  const int srow = wv * 16 + r16;                    // 0..127 (+128 for second call)
  const int skoff = ((c4 ^ ((r16 >> 1) & 3)) << 3);  // pre-swizzled source chunk (u16)
  const int sdst = srow * 32 + (c4 << 3);            // == wave_base + lane*16B
  const size_t gA0 = (size_t)(tm + srow) * 1024 + skoff;
  const size_t gB0 = (size_t)(tn + srow) * 1024 + skoff;

  f32x4 acc[8][3] = {};

#define STAGE(kt, h, b) do {                                     \
    int dA_ = (b) * 16384 + (h) * 8192 + sdst;                   \
    int dB_ = (b) * 12288 + (h) * 6144 + sdst;                   \
    size_t s_ = (size_t)(kt) * 64 + (h) * 32;                    \
    cp16(A + gA0 + s_, As + dA_);                                \
    cp16(A + gA0 + s_ + (size_t)128 * 1024, As + dA_ + 4096);    \
    cp16(Bt + gB0 + s_, Bs + dB_);                               \
    if (wv < 4)                                                  \
      cp16(Bt + gB0 + s_ + (size_t)128 * 1024, Bs + dB_ + 4096); \
  } while (0)

  STAGE(0, 0, 0);
  STAGE(0, 1, 0);
  WAITV(3);   // h0 done (light exact; heavy drains 1 extra of h1 -- safe)
  BAR();

  const int swz8 = (((lane >> 4) ^ ((col >> 1) & 3)) << 3);
  const int abase = (wm * 128 + col) * 32 + swz8;
  const int bbase = (wn * 48 + col) * 32 + swz8;

  for (int t = 0; t < 16; ++t) {
    const int cur = t & 1, nxt = cur ^ 1;
    const u16_t* Ap = As + cur * 16384;
    const u16_t* Bp = Bs + cur * 12288;
    bf16x8 af[4], bf[3];

    // ---- first half-tile: ks=0 (cur.h0), all 8 mt ----
    if (t + 1 < 16) STAGE(t + 1, 0, nxt);
    __builtin_amdgcn_s_setprio(1);
#pragma unroll
    for (int i = 0; i < 4; i++) af[i] = *(const bf16x8*)&Ap[abase + i * 512];
#pragma unroll
    for (int j = 0; j < 3; j++) bf[j] = *(const bf16x8*)&Bp[bbase + j * 512];
#pragma unroll
    for (int i = 0; i < 4; i++)
#pragma unroll
      for (int j = 0; j < 3; j++) acc[i][j] = MFMA(af[i], bf[j], acc[i][j]);
#pragma unroll
    for (int i = 0; i < 4; i++) af[i] = *(const bf16x8*)&Ap[abase + (i + 4) * 512];
#pragma unroll
    for (int i = 0; i < 4; i++)
#pragma unroll
      for (int j = 0; j < 3; j++) acc[i + 4][j] = MFMA(af[i], bf[j], acc[i + 4][j]);
    __builtin_amdgcn_s_setprio(0);
    if (t + 1 < 16) WAITV(3);   // publish cur.h1 (issued last tile); h0(t+1) in flight
    else            WAITV(0);   // final tile: drain h1(15)
    BAR();

    // ---- second half-tile: ks=1 (cur.h1), all 8 mt ----
    if (t + 1 < 16) STAGE(t + 1, 1, nxt);
    __builtin_amdgcn_s_setprio(1);
#pragma unroll
    for (int i = 0; i < 4; i++) af[i] = *(const bf16x8*)&Ap[8192 + abase + i * 512];
#pragma unroll
    for (int j = 0; j < 3; j++) bf[j] = *(const bf16x8*)&Bp[6144 + bbase + j * 512];
#pragma unroll
    for (int i = 0; i < 4; i++)
#pragma unroll
      for (int j = 0; j < 3; j++) acc[i][j] = MFMA(af[i], bf[j], acc[i][j]);
#pragma unroll
    for (int i = 0; i < 4; i++) af[i] = *(const bf16x8*)&Ap[8192 + abase + (i + 4) * 512];
#pragma unroll
    for (int i = 0; i < 4; i++)
#pragma unroll
      for (int j = 0; j < 3; j++) acc[i + 4][j] = MFMA(af[i], bf[j], acc[i + 4][j]);
    __builtin_amdgcn_s_setprio(0);
    if (t + 1 < 16) {
      WAITV(3);   // publish h0(t+1); h1(t+1) stays in flight
      BAR();
    }
  }

#undef STAGE

  // epilogue: per-(wn,nt) fragment mat select (tile can span Q|K|V boundaries)
#pragma unroll
  for (int nt = 0; nt < 3; nt++) {
    int gn = tn + wn * 48 + nt * 16 + col;
    int mat = gn >> 10, d = gn & 1023, h = d >> 6, dk = d & 63;
    const float* bias = mat == 0 ? bq : (mat == 1 ? bk : bv);
    float bb = bias[d];
    if (mat == 2) {
#pragma unroll
      for (int mt = 0; mt < 8; mt++) {
        int gm = tm + wm * 128 + mt * 16 + quad * 4;
        int b = gm >> 11, s = gm & 2047;
        bf16x4 pk4;
#pragma unroll
        for (int r = 0; r < 4; r++) pk4[r] = (__bf16)(acc[mt][nt][r] + bb);
        *(bf16x4*)&Vo[((size_t)((b * 16 + h) * 64 + dk)) * 2048 + s] = pk4;
      }
    } else {
      u16_t* O = mat == 0 ? Qo : Ko;
      const float scl = mat == 0 ? 0.18033688011112042f : 1.0f;  // log2(e)/8 in Q
#pragma unroll
      for (int mt = 0; mt < 8; mt++) {
#pragma unroll
        for (int r = 0; r < 4; r++) {
          int gm = tm + wm * 128 + mt * 16 + quad * 4 + r;
          int b = gm >> 11, s = gm & 2047;
          __bf16 hv = (__bf16)((acc[mt][nt][r] + bb) * scl);
          O[((size_t)((b * 16 + h) * 2048 + s)) * 64 + dk] = *(u16_t*)&hv;
        }
      }
    }
  }
}

// ---------------- kernel 3: fused attention (v14 = v13 + counted-vmcnt steps) ----------------
// Round-12: port the GEMM's T4 scheme. Old per-step __syncthreads = vmcnt(0) drain of
// the prefetch issued that same step. New step: {issue K(t+1),V(t) (8 loads, uniform);
// vmcnt(8) -> completes exactly K(t)+V(t-1), leaves the new 8 in flight; BAR;
// compute; lgkmcnt(0); BAR}. cp16 counts in vmcnt only, so the lgkm wait never drains
// the prefetch. WAR safety: step t+1's writes (issued after BAR2 of step t) target
// buffers whose last readers finished before BAR2 (lgkmcnt(0) drains ds_reads).
// Final step (no K prefetch) waits vmcnt(4); epilogue takes vmcnt(0)+BAR for V(15).
__global__ __launch_bounds__(256, 2) void k_attn(const u16_t* __restrict__ Q,
                                                 const u16_t* __restrict__ K,
                                                 const u16_t* __restrict__ Vt,
                                                 float* __restrict__ out) {
  __shared__ u16_t smem[40960];        // 80 KB
  u16_t* Qs  = smem;                   // 16 KB: Q staging [128][64]
  u16_t* Ksb = smem + 8192;            // 32 KB dbuf: K tiles [2 sub][64k][64d]
  u16_t* Vsb = smem + 24576;           // 32 KB dbuf: V^T tiles [2 sub][64d][64k]
  const int tid = threadIdx.x, lane = tid & 63, wv = tid >> 6;
  const int quad = lane >> 4, col = lane & 15;

  // XCD swizzle: bid&7 = XCD; per XCD: 4 head-groups x 16 qt -> K/V (2 MB) fit 4 MB L2
  const int bid = blockIdx.x;
  const int bh = (bid & 7) + 8 * ((bid >> 3) >> 4);
  const int qt = (bid >> 3) & 15;
  const int b = bh >> 4, h = bh & 15;
  const int r8 = lane >> 3, c8 = lane & 7;

  const u16_t* Qg = Q + ((size_t)bh * 2048 + qt * 128) * 64;
  const u16_t* Kg = K + (size_t)bh * 2048 * 64;
  const u16_t* Vg = Vt + (size_t)bh * 64 * 2048;

  // staging geometry (hoisted): per 64x64 subtile, 2 cp16 per wave
  const int lch  = c8 ^ r8;
  const int row0 = (wv * 2) * 8 + r8, row1 = (wv * 2 + 1) * 8 + r8;
  const int ldst0 = (wv * 2) * 512 + lane * 8;
  const int ldst1 = (wv * 2 + 1) * 512 + lane * 8;
  const int gk0 = row0 * 64 + lch * 8,   gk1 = row1 * 64 + lch * 8;
  const int gv0 = row0 * 2048 + lch * 8, gv1 = row1 * 2048 + lch * 8;

  // prologue: Q (16 chunks, 4/wave) + K tile 0 (both subtiles); full drain once
#pragma unroll
  for (int i = 0; i < 4; i++) {
    int c = wv * 4 + i;
    cp16(Qg + (c * 8 + r8) * 64 + lch * 8, Qs + c * 512 + lane * 8);
  }
  cp16(Kg + gk0, Ksb + ldst0);
  cp16(Kg + gk1, Ksb + ldst1);
  cp16(Kg + 4096 + gk0, Ksb + 4096 + ldst0);
  cp16(Kg + 4096 + gk1, Ksb + 4096 + ldst1);
  __syncthreads();

  // Q fragments (this wave's 32 q = rows wv*32..wv*32+31) -> registers
  bf16x8 qf[2][2];
#pragma unroll
  for (int nt = 0; nt < 2; nt++)
#pragma unroll
    for (int ks = 0; ks < 2; ks++) {
      int row = wv * 32 + nt * 16 + col;
      qf[nt][ks] = *(const bf16x8*)&Qs[row * 64 + (((ks * 4 + quad) ^ (row & 7)) * 8)];
    }

  // hoisted fragment addresses (loop-invariant, valid within each 64x64 subtile)
  int ka[2][4];
#pragma unroll
  for (int ks = 0; ks < 2; ks++)
#pragma unroll
    for (int mt = 0; mt < 4; mt++) {
      int row = mt * 16 + col;
      ka[ks][mt] = row * 64 + (((ks * 4 + quad) ^ (row & 7)) * 8);
    }
  int va0[2][4], va1[2][4];
#pragma unroll
  for (int g = 0; g < 2; g++)
#pragma unroll
    for (int dt = 0; dt < 4; dt++) {
      int row = dt * 16 + col;
      int cc = g * 4 + (quad >> 1);
      va0[g][dt] = row * 64 + ((cc ^ (row & 7)) * 8) + (quad & 1) * 4;
      va1[g][dt] = row * 64 + (((cc + 2) ^ (row & 7)) * 8) + (quad & 1) * 4;
    }

  const short one_bf = (short)0x3F80;  // bf16 1.0
  s16x8 ones8s = {one_bf, one_bf, one_bf, one_bf, one_bf, one_bf, one_bf, one_bf};
  const bf16x8 ones8 = *(bf16x8*)&ones8s;
  const f32x4 z4 = {0.f, 0.f, 0.f, 0.f};

  f32x4 ao[2][4] = {};
  f32x4 dn[2] = {};
  s16x8 pA[2][2][2] = {}, pB[2][2][2] = {};   // P[sub][nt][g], elem = (mt&1)*4+r

#define ATTN_STEP(KT, CUR, PFW, PFR, DO_PV, DO_PRE, WV) do {                          \
    const u16_t* Kc = Ksb + (CUR) * 8192;                                             \
    const u16_t* Vp = Vsb + ((CUR) ^ 1) * 8192;                                       \
    u16_t* Kn = Ksb + ((CUR) ^ 1) * 8192;                                             \
    u16_t* Vn = Vsb + (CUR) * 8192;                                                   \
    if (DO_PRE) {                                                                     \
      const u16_t* kb = Kg + (size_t)((KT) + 1) * 8192;                               \
      cp16(kb + gk0, Kn + ldst0);                                                     \
      cp16(kb + gk1, Kn + ldst1);                                                     \
      cp16(kb + 4096 + gk0, Kn + 4096 + ldst0);                                       \
      cp16(kb + 4096 + gk1, Kn + 4096 + ldst1);                                       \
    }                                                                                 \
    {                                                                                 \
      const u16_t* vb = Vg + (size_t)(KT) * 128;                                      \
      cp16(vb + gv0, Vn + ldst0);                                                     \
      cp16(vb + gv1, Vn + ldst1);                                                     \
      cp16(vb + 64 + gv0, Vn + 4096 + ldst0);                                         \
      cp16(vb + 64 + gv1, Vn + 4096 + ldst1);                                         \
    }                                                                                 \
    WAITV(WV);   /* completes K(KT)+V(KT-1); just-issued loads stay in flight */      \
    BAR();                                                                            \
    __builtin_amdgcn_s_setprio(1);                                                    \
    _Pragma("unroll")                                                                 \
    for (int s = 0; s < 2; s++) {                                                     \
      const u16_t* Ks_ = Kc + s * 4096;                                               \
      f32x4 sc[4][2];                                                                 \
      _Pragma("unroll")                                                               \
      for (int ks = 0; ks < 2; ks++) {                                                \
        bf16x8 kf[4];                                                                 \
        _Pragma("unroll")                                                             \
        for (int mt = 0; mt < 4; mt++) kf[mt] = *(const bf16x8*)&Ks_[ka[ks][mt]];     \
        _Pragma("unroll")                                                             \
        for (int mt = 0; mt < 4; mt++)                                                \
          _Pragma("unroll")                                                           \
          for (int nt = 0; nt < 2; nt++)                                              \
            sc[mt][nt] = ks ? MFMA(kf[mt], qf[nt][1], sc[mt][nt])                     \
                            : MFMA(kf[mt], qf[nt][0], z4);                            \
      }                                                                               \
      _Pragma("unroll")                                                               \
      for (int mt = 0; mt < 4; mt++)                                                  \
        _Pragma("unroll")                                                             \
        for (int nt = 0; nt < 2; nt++)                                                \
          _Pragma("unroll")                                                           \
          for (int r = 0; r < 4; r++) {                                               \
            __bf16 e = (__bf16)__builtin_amdgcn_exp2f(sc[mt][nt][r]);                 \
            PFW[s][nt][mt >> 1][(mt & 1) * 4 + r] = *(short*)&e;                      \
          }                                                                           \
    }                                                                                 \
    if (DO_PV) {                                                                      \
      _Pragma("unroll")                                                               \
      for (int s = 0; s < 2; s++) {                                                   \
        const u16_t* Vs_ = Vp + s * 4096;                                             \
        bf16x8 pa00 = b8(PFR[s][0][0]), pa01 = b8(PFR[s][0][1]);                      \
        bf16x8 pa10 = b8(PFR[s][1][0]), pa11 = b8(PFR[s][1][1]);                      \
        _Pragma("unroll")                                                             \
        for (int dt = 0; dt < 4; dt++) {                                              \
          bf16x8 vv0 = cat8(*(const s16x4*)&Vs_[va0[0][dt]],                          \
                            *(const s16x4*)&Vs_[va1[0][dt]]);                         \
          bf16x8 vv1 = cat8(*(const s16x4*)&Vs_[va0[1][dt]],                          \
                            *(const s16x4*)&Vs_[va1[1][dt]]);                         \
          ao[0][dt] = MFMA(pa00, vv0, ao[0][dt]);                                     \
          ao[0][dt] = MFMA(pa01, vv1, ao[0][dt]);                                     \
          ao[1][dt] = MFMA(pa10, vv0, ao[1][dt]);                                     \
          ao[1][dt] = MFMA(pa11, vv1, ao[1][dt]);                                     \
        }                                                                             \
      }                                                                               \
    }                                                                                 \
    _Pragma("unroll")                                                                 \
    for (int s = 0; s < 2; s++) {                                                     \
      dn[0] = MFMA(b8(PFW[s][0][0]), ones8, dn[0]);                                   \
      dn[0] = MFMA(b8(PFW[s][0][1]), ones8, dn[0]);                                   \
      dn[1] = MFMA(b8(PFW[s][1][0]), ones8, dn[1]);                                   \
      dn[1] = MFMA(b8(PFW[s][1][1]), ones8, dn[1]);                                   \
    }                                                                                 \
    __builtin_amdgcn_s_setprio(0);                                                    \
    WAITL();   /* ds_reads of cur buffers done before next step's overwrites */       \
    BAR();                                                                            \
  } while (0)

  // 16 steps over 128-key tiles; peeled first (no PV) and last (no K prefetch)
  ATTN_STEP(0, 0, pA, pB, 0, 1, 8);
#pragma unroll 1
  for (int kt2 = 0; kt2 < 7; kt2++) {
    int kt0 = kt2 * 2 + 1;
    ATTN_STEP(kt0,     1, pB, pA, 1, 1, 8);
    ATTN_STEP(kt0 + 1, 0, pA, pB, 1, 1, 8);
  }
  ATTN_STEP(15, 1, pB, pA, 1, 0, 4);
#undef ATTN_STEP

  // drain V(15) and make all waves' staging visible
  WAITV(0);
  BAR();

  // epilogue PV: P(15) in pB, V(15) in Vsb buffer 1
  {
    const u16_t* Vp = Vsb + 8192;
#pragma unroll
    for (int s = 0; s < 2; s++) {
      const u16_t* Vs_ = Vp + s * 4096;
      bf16x8 pa00 = b8(pB[s][0][0]), pa01 = b8(pB[s][0][1]);
      bf16x8 pa10 = b8(pB[s][1][0]), pa11 = b8(pB[s][1][1]);
#pragma unroll
      for (int dt = 0; dt < 4; dt++) {
        bf16x8 vv0 = cat8(*(const s16x4*)&Vs_[va0[0][dt]], *(const s16x4*)&Vs_[va1[0][dt]]);
        bf16x8 vv1 = cat8(*(const s16x4*)&Vs_[va0[1][dt]], *(const s16x4*)&Vs_[va1[1][dt]]);
        ao[0][dt] = MFMA(pa00, vv0, ao[0][dt]);
        ao[0][dt] = MFMA(pa01, vv1, ao[0][dt]);
        ao[1][dt] = MFMA(pa10, vv0, ao[1][dt]);
        ao[1][dt] = MFMA(pa11, vv1, ao[1][dt]);
      }
    }
  }

  // epilogue: direct normalize + store (no cross-wave merge)
#pragma unroll
  for (int nt = 0; nt < 2; nt++) {
    float inv[4];
#pragma unroll
    for (int r = 0; r < 4; r++)
      inv[r] = 1.0f / (dn[nt][r] + 1e-8f);
#pragma unroll
    for (int dt = 0; dt < 4; dt++) {
#pragma unroll
      for (int r = 0; r < 4; r++) {
        float v = ao[nt][dt][r] * inv[r];
        int s = qt * 128 + wv * 32 + nt * 16 + quad * 4 + r;
        out[((size_t)b * 2048 + s) * 1024 + h * 64 + dt * 16 + col] = v;
      }
    }
  }
}

// ---------------- launcher ----------------
extern "C" void kernel_launch(void* const* d_in, const int* in_sizes, int n_in,
                              void* d_out, int out_size, void* d_ws, size_t ws_size,
                              hipStream_t stream) {
  const float* x  = (const float*)d_in[0];
  const float* Wq = (const float*)d_in[1];
  const float* bq = (const float*)d_in[2];
  const float* Wk = (const float*)d_in[3];
  const float* bk = (const float*)d_in[4];
  const float* Wv = (const float*)d_in[5];
  const float* bv = (const float*)d_in[6];
  float* out = (float*)d_out;

  char* ws = (char*)d_ws;
  u16_t* xb  = (u16_t*)(ws);                 // 8 MB   x bf16 [4096][1024]
  u16_t* Wt  = (u16_t*)(ws + 8388608);       // 6 MB   Wt bf16 [3072][1024]
  u16_t* Qb  = (u16_t*)(ws + 14680064);      // 8 MB   Q bf16 [bh][s][dk] (pre-scaled)
  u16_t* Kb  = (u16_t*)(ws + 23068672);      // 8 MB   K bf16 [bh][s][dk]
  u16_t* Vtb = (u16_t*)(ws + 31457280);      // 8 MB   V^T bf16 [bh][dk][s]

  hipLaunchKernelGGL(k_prep, dim3(4864), dim3(256), 0, stream, x, Wq, Wk, Wv, xb, Wt);
  hipLaunchKernelGGL(k_gemm_qkv, dim3(256), dim3(512), 0, stream,
                     xb, Wt, bq, bk, bv, Qb, Kb, Vtb);
  hipLaunchKernelGGL(k_attn, dim3(512), dim3(256), 0, stream, Qb, Kb, Vtb, out);
}

// Round 14
// 154.966 us; speedup vs baseline: 1.0088x; 1.0088x over previous
//
#include <hip/hip_runtime.h>
#include <hip/hip_bf16.h>
#include <stdint.h>

typedef __bf16 bf16x8 __attribute__((ext_vector_type(8)));
typedef __bf16 bf16x4 __attribute__((ext_vector_type(4)));
typedef float  f32x4  __attribute__((ext_vector_type(4)));
typedef short  s16x4  __attribute__((ext_vector_type(4)));
typedef short  s16x8  __attribute__((ext_vector_type(8)));
typedef unsigned short u16_t;

#define MFMA(a, b, c)   __builtin_amdgcn_mfma_f32_16x16x32_bf16((a), (b), (c), 0, 0, 0)

// sync primitives (two-level stringize so macro args expand before #)
#define BAR()     asm volatile("s_barrier" ::: "memory")
#define WAITV_(N) asm volatile("s_waitcnt vmcnt(" #N ")" ::: "memory")
#define WAITV(N)  WAITV_(N)
#define WAITL()   asm volatile("s_waitcnt lgkmcnt(0)" ::: "memory")

// concat two s16x4 halves into a bf16x8 MFMA operand
__device__ __forceinline__ bf16x8 cat8(s16x4 a, s16x4 b) {
  s16x8 t = __builtin_shufflevector(a, b, 0, 1, 2, 3, 4, 5, 6, 7);
  return *(bf16x8*)&t;
}
__device__ __forceinline__ bf16x8 b8(s16x8 v) {
  bf16x8 r; __builtin_memcpy(&r, &v, 16); return r;
}

// async global->LDS, 16B per lane; LDS dest is wave-uniform base + lane*16
__device__ __forceinline__ void cp16(const void* g, void* l) {
  __builtin_amdgcn_global_load_lds(
      (const __attribute__((address_space(1))) unsigned int*)g,
      (__attribute__((address_space(3))) unsigned int*)l, 16, 0, 0);
}

// ---------------- kernel 1: fused x-convert + W-transpose-convert ----------------
__global__ __launch_bounds__(256) void k_prep(const float* __restrict__ x,
                                              const float* __restrict__ W0,
                                              const float* __restrict__ W1,
                                              const float* __restrict__ W2,
                                              u16_t* __restrict__ xb,
                                              u16_t* __restrict__ Wt) {
  __shared__ u16_t T[64][65];
  int bx = blockIdx.x, t = threadIdx.x;
  if (bx < 4096) {
    int i = bx * 256 + t;
    float4 f = ((const float4*)x)[i];
    bf16x4 o = {(__bf16)f.x, (__bf16)f.y, (__bf16)f.z, (__bf16)f.w};
    *(bf16x4*)&xb[(size_t)i * 4] = o;
    return;
  }
  int j = bx - 4096;
  int nx = j & 15, ny = (j >> 4) & 15, z = j >> 8;
  const float* W = z == 0 ? W0 : (z == 1 ? W1 : W2);
  int k0 = ny * 64, n0 = nx * 64;
#pragma unroll
  for (int i = 0; i < 16; i++) {
    int e = i * 256 + t, r = e >> 6, c = e & 63;
    __bf16 hv = (__bf16)W[(size_t)(k0 + r) * 1024 + n0 + c];
    T[r][c] = *(u16_t*)&hv;
  }
  __syncthreads();
  size_t base = ((size_t)z * 1024 + n0) * 1024 + k0;
#pragma unroll
  for (int i = 0; i < 16; i++) {
    int e = i * 256 + t, r = e >> 6, c = e & 63;
    Wt[base + (size_t)r * 1024 + c] = T[c][r];
  }
}

// ---------------- kernel 2: fused QKV GEMM, 256x192 tile, 8-wave, 2-barrier/tile ----------------
// (round-11 version, confirmed win. Unchanged.)
__global__ __launch_bounds__(512, 2) void k_gemm_qkv(
    const u16_t* __restrict__ A, const u16_t* __restrict__ Bt,
    const float* __restrict__ bq, const float* __restrict__ bk,
    const float* __restrict__ bv,
    u16_t* __restrict__ Qo, u16_t* __restrict__ Ko, u16_t* __restrict__ Vo) {
  __shared__ u16_t smem[57344];          // 112 KB
  u16_t* As = smem;                      // [buf:16384][half:8192][row*32 + chunk*8], 256 rows
  u16_t* Bs = smem + 32768;              // [buf:12288][half:6144][row*32 + chunk*8], 192 rows

  const int tid = threadIdx.x, lane = tid & 63, wv = tid >> 6;
  const int quad = lane >> 4, col = lane & 15;
  const int wm = wv >> 2, wn = wv & 3;   // 2x4 wave grid; wave owns 128x48 of C

  // XCD swizzle: 256 blocks, 32 consecutive wg per XCD
  int bid = blockIdx.x;
  int wg = (bid & 7) * 32 + (bid >> 3);
  const int tn = (wg & 15) * 192, tm = (wg >> 4) << 8;

  const int r16 = lane >> 2, c4 = lane & 3;
  const int srow = wv * 16 + r16;                    // 0..127 (+128 for second call)
  const int skoff = ((c4 ^ ((r16 >> 1) & 3)) << 3);  // pre-swizzled source chunk (u16)
  const int sdst = srow * 32 + (c4 << 3);            // == wave_base + lane*16B
  const size_t gA0 = (size_t)(tm + srow) * 1024 + skoff;
  const size_t gB0 = (size_t)(tn + srow) * 1024 + skoff;

  f32x4 acc[8][3] = {};

#define STAGE(kt, h, b) do {                                     \
    int dA_ = (b) * 16384 + (h) * 8192 + sdst;                   \
    int dB_ = (b) * 12288 + (h) * 6144 + sdst;                   \
    size_t s_ = (size_t)(kt) * 64 + (h) * 32;                    \
    cp16(A + gA0 + s_, As + dA_);                                \
    cp16(A + gA0 + s_ + (size_t)128 * 1024, As + dA_ + 4096);    \
    cp16(Bt + gB0 + s_, Bs + dB_);                               \
    if (wv < 4)                                                  \
      cp16(Bt + gB0 + s_ + (size_t)128 * 1024, Bs + dB_ + 4096); \
  } while (0)

  STAGE(0, 0, 0);
  STAGE(0, 1, 0);
  WAITV(3);   // h0 done (light exact; heavy drains 1 extra of h1 -- safe)
  BAR();

  const int swz8 = (((lane >> 4) ^ ((col >> 1) & 3)) << 3);
  const int abase = (wm * 128 + col) * 32 + swz8;
  const int bbase = (wn * 48 + col) * 32 + swz8;

  for (int t = 0; t < 16; ++t) {
    const int cur = t & 1, nxt = cur ^ 1;
    const u16_t* Ap = As + cur * 16384;
    const u16_t* Bp = Bs + cur * 12288;
    bf16x8 af[4], bf[3];

    // ---- first half-tile: ks=0 (cur.h0), all 8 mt ----
    if (t + 1 < 16) STAGE(t + 1, 0, nxt);
    __builtin_amdgcn_s_setprio(1);
#pragma unroll
    for (int i = 0; i < 4; i++) af[i] = *(const bf16x8*)&Ap[abase + i * 512];
#pragma unroll
    for (int j = 0; j < 3; j++) bf[j] = *(const bf16x8*)&Bp[bbase + j * 512];
#pragma unroll
    for (int i = 0; i < 4; i++)
#pragma unroll
      for (int j = 0; j < 3; j++) acc[i][j] = MFMA(af[i], bf[j], acc[i][j]);
#pragma unroll
    for (int i = 0; i < 4; i++) af[i] = *(const bf16x8*)&Ap[abase + (i + 4) * 512];
#pragma unroll
    for (int i = 0; i < 4; i++)
#pragma unroll
      for (int j = 0; j < 3; j++) acc[i + 4][j] = MFMA(af[i], bf[j], acc[i + 4][j]);
    __builtin_amdgcn_s_setprio(0);
    if (t + 1 < 16) WAITV(3);   // publish cur.h1 (issued last tile); h0(t+1) in flight
    else            WAITV(0);   // final tile: drain h1(15)
    BAR();

    // ---- second half-tile: ks=1 (cur.h1), all 8 mt ----
    if (t + 1 < 16) STAGE(t + 1, 1, nxt);
    __builtin_amdgcn_s_setprio(1);
#pragma unroll
    for (int i = 0; i < 4; i++) af[i] = *(const bf16x8*)&Ap[8192 + abase + i * 512];
#pragma unroll
    for (int j = 0; j < 3; j++) bf[j] = *(const bf16x8*)&Bp[6144 + bbase + j * 512];
#pragma unroll
    for (int i = 0; i < 4; i++)
#pragma unroll
      for (int j = 0; j < 3; j++) acc[i][j] = MFMA(af[i], bf[j], acc[i][j]);
#pragma unroll
    for (int i = 0; i < 4; i++) af[i] = *(const bf16x8*)&Ap[8192 + abase + (i + 4) * 512];
#pragma unroll
    for (int i = 0; i < 4; i++)
#pragma unroll
      for (int j = 0; j < 3; j++) acc[i + 4][j] = MFMA(af[i], bf[j], acc[i + 4][j]);
    __builtin_amdgcn_s_setprio(0);
    if (t + 1 < 16) {
      WAITV(3);   // publish h0(t+1); h1(t+1) stays in flight
      BAR();
    }
  }

#undef STAGE

  // epilogue: per-(wn,nt) fragment mat select (tile can span Q|K|V boundaries)
#pragma unroll
  for (int nt = 0; nt < 3; nt++) {
    int gn = tn + wn * 48 + nt * 16 + col;
    int mat = gn >> 10, d = gn & 1023, h = d >> 6, dk = d & 63;
    const float* bias = mat == 0 ? bq : (mat == 1 ? bk : bv);
    float bb = bias[d];
    if (mat == 2) {
#pragma unroll
      for (int mt = 0; mt < 8; mt++) {
        int gm = tm + wm * 128 + mt * 16 + quad * 4;
        int b = gm >> 11, s = gm & 2047;
        bf16x4 pk4;
#pragma unroll
        for (int r = 0; r < 4; r++) pk4[r] = (__bf16)(acc[mt][nt][r] + bb);
        *(bf16x4*)&Vo[((size_t)((b * 16 + h) * 64 + dk)) * 2048 + s] = pk4;
      }
    } else {
      u16_t* O = mat == 0 ? Qo : Ko;
      const float scl = mat == 0 ? 0.18033688011112042f : 1.0f;  // log2(e)/8 in Q
#pragma unroll
      for (int mt = 0; mt < 8; mt++) {
#pragma unroll
        for (int r = 0; r < 4; r++) {
          int gm = tm + wm * 128 + mt * 16 + quad * 4 + r;
          int b = gm >> 11, s = gm & 2047;
          __bf16 hv = (__bf16)((acc[mt][nt][r] + bb) * scl);
          O[((size_t)((b * 16 + h) * 2048 + s)) * 64 + dk] = *(u16_t*)&hv;
        }
      }
    }
  }
}

// ---------------- kernel 3: fused attention (v15 = v14 + QBLK 256, 8-wave, AITER geometry) ----------------
// 8 waves x 32 full q-rows = 256 q/block; grid 256 = 1 block/CU. Per-wave compute
// identical to v14 (32q x 128k per step); staging per wave per step halves 8 -> 4 cp16
// (K: 1/sub, V: 1/sub). Counted waits: steady WAITV(4) completes {K(t),V(t-1)}, leaves
// the 4 new in flight; final step (V only) WAITV(2); epilogue WAITV(0). LDS 96 KB
// (Q 32 + K dbuf 32 + V dbuf 32). SIMD TLP unchanged (2 waves/SIMD); AITER ts_qo=256
// precedent (m243).
__global__ __launch_bounds__(512, 1) void k_attn(const u16_t* __restrict__ Q,
                                                 const u16_t* __restrict__ K,
                                                 const u16_t* __restrict__ Vt,
                                                 float* __restrict__ out) {
  __shared__ u16_t smem[49152];        // 96 KB
  u16_t* Qs  = smem;                   // 32 KB: Q staging [256][64]
  u16_t* Ksb = smem + 16384;           // 32 KB dbuf: K tiles [2 sub][64k][64d]
  u16_t* Vsb = smem + 32768;           // 32 KB dbuf: V^T tiles [2 sub][64d][64k]
  const int tid = threadIdx.x, lane = tid & 63, wv = tid >> 6;   // wv in [0,8)
  const int quad = lane >> 4, col = lane & 15;

  // XCD swizzle: bid&7 = XCD; per XCD: 4 heads x 8 qt -> K/V (2 MB) fit 4 MB L2
  const int bid = blockIdx.x;
  const int bh = (bid & 7) + 8 * ((bid >> 3) >> 3);
  const int qt = (bid >> 3) & 7;
  const int b = bh >> 4, h = bh & 15;
  const int r8 = lane >> 3, c8 = lane & 7;

  const u16_t* Qg = Q + ((size_t)bh * 2048 + qt * 256) * 64;
  const u16_t* Kg = K + (size_t)bh * 2048 * 64;
  const u16_t* Vg = Vt + (size_t)bh * 64 * 2048;

  // staging geometry (hoisted): per 64x64 subtile, 1 cp16 per wave (8 waves cover it)
  const int lch  = c8 ^ r8;
  const int row0 = wv * 8 + r8;              // 0..63
  const int ldst0 = wv * 512 + lane * 8;     // wave chunk of 1 KB
  const int gk0 = row0 * 64 + lch * 8;
  const int gv0 = row0 * 2048 + lch * 8;

  // prologue: Q (32 chunks, 4/wave) + K tile 0 (both subtiles); full drain once
#pragma unroll
  for (int i = 0; i < 4; i++) {
    int c = wv * 4 + i;
    cp16(Qg + (c * 8 + r8) * 64 + lch * 8, Qs + c * 512 + lane * 8);
  }
  cp16(Kg + gk0, Ksb + ldst0);
  cp16(Kg + 4096 + gk0, Ksb + 4096 + ldst0);
  __syncthreads();

  // Q fragments (this wave's 32 q = rows wv*32..wv*32+31) -> registers
  bf16x8 qf[2][2];
#pragma unroll
  for (int nt = 0; nt < 2; nt++)
#pragma unroll
    for (int ks = 0; ks < 2; ks++) {
      int row = wv * 32 + nt * 16 + col;
      qf[nt][ks] = *(const bf16x8*)&Qs[row * 64 + (((ks * 4 + quad) ^ (row & 7)) * 8)];
    }

  // hoisted fragment addresses (loop-invariant, valid within each 64x64 subtile)
  int ka[2][4];
#pragma unroll
  for (int ks = 0; ks < 2; ks++)
#pragma unroll
    for (int mt = 0; mt < 4; mt++) {
      int row = mt * 16 + col;
      ka[ks][mt] = row * 64 + (((ks * 4 + quad) ^ (row & 7)) * 8);
    }
  int va0[2][4], va1[2][4];
#pragma unroll
  for (int g = 0; g < 2; g++)
#pragma unroll
    for (int dt = 0; dt < 4; dt++) {
      int row = dt * 16 + col;
      int cc = g * 4 + (quad >> 1);
      va0[g][dt] = row * 64 + ((cc ^ (row & 7)) * 8) + (quad & 1) * 4;
      va1[g][dt] = row * 64 + (((cc + 2) ^ (row & 7)) * 8) + (quad & 1) * 4;
    }

  const short one_bf = (short)0x3F80;  // bf16 1.0
  s16x8 ones8s = {one_bf, one_bf, one_bf, one_bf, one_bf, one_bf, one_bf, one_bf};
  const bf16x8 ones8 = *(bf16x8*)&ones8s;
  const f32x4 z4 = {0.f, 0.f, 0.f, 0.f};

  f32x4 ao[2][4] = {};
  f32x4 dn[2] = {};
  s16x8 pA[2][2][2] = {}, pB[2][2][2] = {};   // P[sub][nt][g], elem = (mt&1)*4+r

#define ATTN_STEP(KT, CUR, PFW, PFR, DO_PV, DO_PRE, WV) do {                          \
    const u16_t* Kc = Ksb + (CUR) * 8192;                                             \
    const u16_t* Vp = Vsb + ((CUR) ^ 1) * 8192;                                       \
    u16_t* Kn = Ksb + ((CUR) ^ 1) * 8192;                                             \
    u16_t* Vn = Vsb + (CUR) * 8192;                                                   \
    if (DO_PRE) {                                                                     \
      const u16_t* kb = Kg + (size_t)((KT) + 1) * 8192;                               \
      cp16(kb + gk0, Kn + ldst0);                                                     \
      cp16(kb + 4096 + gk0, Kn + 4096 + ldst0);                                       \
    }                                                                                 \
    {                                                                                 \
      const u16_t* vb = Vg + (size_t)(KT) * 128;                                      \
      cp16(vb + gv0, Vn + ldst0);                                                     \
      cp16(vb + 64 + gv0, Vn + 4096 + ldst0);                                        \
    }                                                                                 \
    WAITV(WV);   /* completes K(KT)+V(KT-1); just-issued loads stay in flight */      \
    BAR();                                                                            \
    __builtin_amdgcn_s_setprio(1);                                                    \
    _Pragma("unroll")                                                                 \
    for (int s = 0; s < 2; s++) {                                                     \
      const u16_t* Ks_ = Kc + s * 4096;                                               \
      f32x4 sc[4][2];                                                                 \
      _Pragma("unroll")                                                               \
      for (int ks = 0; ks < 2; ks++) {                                                \
        bf16x8 kf[4];                                                                 \
        _Pragma("unroll")                                                             \
        for (int mt = 0; mt < 4; mt++) kf[mt] = *(const bf16x8*)&Ks_[ka[ks][mt]];     \
        _Pragma("unroll")                                                             \
        for (int mt = 0; mt < 4; mt++)                                                \
          _Pragma("unroll")                                                           \
          for (int nt = 0; nt < 2; nt++)                                              \
            sc[mt][nt] = ks ? MFMA(kf[mt], qf[nt][1], sc[mt][nt])                     \
                            : MFMA(kf[mt], qf[nt][0], z4);                            \
      }                                                                               \
      _Pragma("unroll")                                                               \
      for (int mt = 0; mt < 4; mt++)                                                  \
        _Pragma("unroll")                                                             \
        for (int nt = 0; nt < 2; nt++)                                                \
          _Pragma("unroll")                                                           \
          for (int r = 0; r < 4; r++) {                                               \
            __bf16 e = (__bf16)__builtin_amdgcn_exp2f(sc[mt][nt][r]);                 \
            PFW[s][nt][mt >> 1][(mt & 1) * 4 + r] = *(short*)&e;                      \
          }                                                                           \
    }                                                                                 \
    if (DO_PV) {                                                                      \
      _Pragma("unroll")                                                               \
      for (int s = 0; s < 2; s++) {                                                   \
        const u16_t* Vs_ = Vp + s * 4096;                                             \
        bf16x8 pa00 = b8(PFR[s][0][0]), pa01 = b8(PFR[s][0][1]);                      \
        bf16x8 pa10 = b8(PFR[s][1][0]), pa11 = b8(PFR[s][1][1]);                      \
        _Pragma("unroll")                                                             \
        for (int dt = 0; dt < 4; dt++) {                                              \
          bf16x8 vv0 = cat8(*(const s16x4*)&Vs_[va0[0][dt]],                          \
                            *(const s16x4*)&Vs_[va1[0][dt]]);                         \
          bf16x8 vv1 = cat8(*(const s16x4*)&Vs_[va0[1][dt]],                          \
                            *(const s16x4*)&Vs_[va1[1][dt]]);                         \
          ao[0][dt] = MFMA(pa00, vv0, ao[0][dt]);                                     \
          ao[0][dt] = MFMA(pa01, vv1, ao[0][dt]);                                     \
          ao[1][dt] = MFMA(pa10, vv0, ao[1][dt]);                                     \
          ao[1][dt] = MFMA(pa11, vv1, ao[1][dt]);                                     \
        }                                                                             \
      }                                                                               \
    }                                                                                 \
    _Pragma("unroll")                                                                 \
    for (int s = 0; s < 2; s++) {                                                     \
      dn[0] = MFMA(b8(PFW[s][0][0]), ones8, dn[0]);                                   \
      dn[0] = MFMA(b8(PFW[s][0][1]), ones8, dn[0]);                                   \
      dn[1] = MFMA(b8(PFW[s][1][0]), ones8, dn[1]);                                   \
      dn[1] = MFMA(b8(PFW[s][1][1]), ones8, dn[1]);                                   \
    }                                                                                 \
    __builtin_amdgcn_s_setprio(0);                                                    \
    WAITL();   /* ds_reads of cur buffers done before next step's overwrites */       \
    BAR();                                                                            \
  } while (0)

  // 16 steps over 128-key tiles; peeled first (no PV) and last (no K prefetch)
  ATTN_STEP(0, 0, pA, pB, 0, 1, 4);
#pragma unroll 1
  for (int kt2 = 0; kt2 < 7; kt2++) {
    int kt0 = kt2 * 2 + 1;
    ATTN_STEP(kt0,     1, pB, pA, 1, 1, 4);
    ATTN_STEP(kt0 + 1, 0, pA, pB, 1, 1, 4);
  }
  ATTN_STEP(15, 1, pB, pA, 1, 0, 2);
#undef ATTN_STEP

  // drain V(15) and make all waves' staging visible
  WAITV(0);
  BAR();

  // epilogue PV: P(15) in pB, V(15) in Vsb buffer 1
  {
    const u16_t* Vp = Vsb + 8192;
#pragma unroll
    for (int s = 0; s < 2; s++) {
      const u16_t* Vs_ = Vp + s * 4096;
      bf16x8 pa00 = b8(pB[s][0][0]), pa01 = b8(pB[s][0][1]);
      bf16x8 pa10 = b8(pB[s][1][0]), pa11 = b8(pB[s][1][1]);
#pragma unroll
      for (int dt = 0; dt < 4; dt++) {
        bf16x8 vv0 = cat8(*(const s16x4*)&Vs_[va0[0][dt]], *(const s16x4*)&Vs_[va1[0][dt]]);
        bf16x8 vv1 = cat8(*(const s16x4*)&Vs_[va0[1][dt]], *(const s16x4*)&Vs_[va1[1][dt]]);
        ao[0][dt] = MFMA(pa00, vv0, ao[0][dt]);
        ao[0][dt] = MFMA(pa01, vv1, ao[0][dt]);
        ao[1][dt] = MFMA(pa10, vv0, ao[1][dt]);
        ao[1][dt] = MFMA(pa11, vv1, ao[1][dt]);
      }
    }
  }

  // epilogue: direct normalize + store (no cross-wave merge)
#pragma unroll
  for (int nt = 0; nt < 2; nt++) {
    float inv[4];
#pragma unroll
    for (int r = 0; r < 4; r++)
      inv[r] = 1.0f / (dn[nt][r] + 1e-8f);
#pragma unroll
    for (int dt = 0; dt < 4; dt++) {
#pragma unroll
      for (int r = 0; r < 4; r++) {
        float v = ao[nt][dt][r] * inv[r];
        int s = qt * 256 + wv * 32 + nt * 16 + quad * 4 + r;
        out[((size_t)b * 2048 + s) * 1024 + h * 64 + dt * 16 + col] = v;
      }
    }
  }
}

// ---------------- launcher ----------------
extern "C" void kernel_launch(void* const* d_in, const int* in_sizes, int n_in,
                              void* d_out, int out_size, void* d_ws, size_t ws_size,
                              hipStream_t stream) {
  const float* x  = (const float*)d_in[0];
  const float* Wq = (const float*)d_in[1];
  const float* bq = (const float*)d_in[2];
  const float* Wk = (const float*)d_in[3];
  const float* bk = (const float*)d_in[4];
  const float* Wv = (const float*)d_in[5];
  const float* bv = (const float*)d_in[6];
  float* out = (float*)d_out;

  char* ws = (char*)d_ws;
  u16_t* xb  = (u16_t*)(ws);                 // 8 MB   x bf16 [4096][1024]
  u16_t* Wt  = (u16_t*)(ws + 8388608);       // 6 MB   Wt bf16 [3072][1024]
  u16_t* Qb  = (u16_t*)(ws + 14680064);      // 8 MB   Q bf16 [bh][s][dk] (pre-scaled)
  u16_t* Kb  = (u16_t*)(ws + 23068672);      // 8 MB   K bf16 [bh][s][dk]
  u16_t* Vtb = (u16_t*)(ws + 31457280);      // 8 MB   V^T bf16 [bh][dk][s]

  hipLaunchKernelGGL(k_prep, dim3(4864), dim3(256), 0, stream, x, Wq, Wk, Wv, xb, Wt);
  hipLaunchKernelGGL(k_gemm_qkv, dim3(256), dim3(512), 0, stream,
                     xb, Wt, bq, bk, bv, Qb, Kb, Vtb);
  hipLaunchKernelGGL(k_attn, dim3(256), dim3(512), 0, stream, Qb, Kb, Vtb, out);
}